// Round 11
// baseline (137.135 us; speedup 1.0000x reference)
//
#include <hip/hip_runtime.h>
#include <math.h>

// MaxPool3d: in (2,32,128,128,128) f32, k=3 s2 p1 (-inf pad) -> out (2,32,64,64,64) f32
// v11 = v10 (h-tile 16, 512-thread blocks) with KPB=16: d-edge overfetch
// 17/16 -> 33/32, modeled traffic 625 -> 608 MB. 1024 blocks x 8 waves =
// 4 blocks/CU = 32 waves/CU (<=64 VGPR, no spill). Single-variable vs v10.

#define D_IN 128
#define H_IN 128
#define W_IN 128
#define HW (H_IN * W_IN)
#define D_OUT 64
#define H_OUT 64
#define W_OUT 64
#define NC 64   // 2*32
#define KPB 16  // d_out windows per block

typedef float vf2 __attribute__((ext_vector_type(2)));

struct P3 { float4 r0, r1, r2; };

__device__ __forceinline__ P3 loadPlane(const float* __restrict__ p, int r0off) {
    P3 v;
    v.r0 = *reinterpret_cast<const float4*>(p + r0off);   // row 2h-1 (clamped if pad)
    v.r1 = *reinterpret_cast<const float4*>(p + W_IN);    // row 2h
    v.r2 = *reinterpret_cast<const float4*>(p + 2 * W_IN);// row 2h+1
    return v;
}

__device__ __forceinline__ float rowL(float4 v, int t) {
    float left = __shfl_up(v.w, 1, 64);   // neighbor's x[4t-1]
    if (t == 0) left = -INFINITY;         // -inf pad at w=-1 (kills cross-row garbage too)
    return fmaxf(left, fmaxf(v.x, v.y));  // w_out = 2t
}
__device__ __forceinline__ float rowR(float4 v) {
    return fmaxf(v.y, fmaxf(v.z, v.w));   // w_out = 2t+1
}

// (h,w)-pooled pair {w_out=2t, 2t+1} of one plane
__device__ __forceinline__ vf2 poolPlane(const P3& v, int t, bool h0ok) {
    float ax0 = rowL(v.r0, t), ay0 = rowR(v.r0);
    if (!h0ok) { ax0 = -INFINITY; ay0 = -INFINITY; }   // row -1 is -inf pad
    float ax1 = rowL(v.r1, t), ay1 = rowR(v.r1);
    float ax2 = rowL(v.r2, t), ay2 = rowR(v.r2);
    vf2 o;
    o.x = fmaxf(ax0, fmaxf(ax1, ax2));
    o.y = fmaxf(ay0, fmaxf(ay1, ay2));
    return o;
}

__device__ __forceinline__ vf2 vmax2(vf2 a, vf2 b) {
    vf2 o; o.x = fmaxf(a.x, b.x); o.y = fmaxf(a.y, b.y); return o;
}

__global__ __launch_bounds__(512, 8) void maxpool3d_k3s2p1_v11(const float* __restrict__ x,
                                                               float* __restrict__ out) {
    const int t  = threadIdx.x & 31;   // w-pair index: w_out = 2t, 2t+1
    const int hy = threadIdx.x >> 5;   // h row within block (0..15)
    const int h_out = blockIdx.x * 16 + hy;
    const int k0    = blockIdx.y * KPB;
    const int nc    = blockIdx.z;

    const int h_in0 = 2 * h_out - 1;
    const bool h0ok = (h_in0 >= 0);
    const int r0off = h0ok ? 0 : W_IN;   // clamp pad row's address (value replaced)

    const float* __restrict__ base =
        x + (size_t)nc * (D_IN * HW) + (ptrdiff_t)h_in0 * W_IN + 4 * t;
    float* __restrict__ obase =
        out + (size_t)nc * (D_OUT * H_OUT * W_OUT) + (size_t)h_out * W_OUT + 2 * t;

    auto storeK = [&](int k, vf2 o) {
        __builtin_nontemporal_store(o, reinterpret_cast<vf2*>(obase + (size_t)k * (H_OUT * W_OUT)));
    };

    P3 A, B;
    vf2 acc;
    // Invariant: acc = max over planes {2k0-1, 2k0}; A holds plane 2k0+1 (issued).
    if (k0 == 0) {
        A = loadPlane(base, r0off);                           // plane 0 (plane -1 = pad)
        P3 A1 = loadPlane(base + HW, r0off);                  // plane 1, issued early
        acc = poolPlane(A, t, h0ok);
        A = A1;
    } else {
        A = loadPlane(base + (size_t)(2 * k0 - 1) * HW, r0off);
        B = loadPlane(base + (size_t)(2 * k0) * HW, r0off);
        vf2 a0 = poolPlane(A, t, h0ok);
        A = loadPlane(base + (size_t)(2 * k0 + 1) * HW, r0off);
        acc = vmax2(a0, poolPlane(B, t, h0ok));
    }

#pragma unroll 1
    for (int k = k0; k < k0 + KPB - 1; ++k) {
        B = loadPlane(base + (size_t)(2 * k + 2) * HW, r0off);  // issue next-plane loads
        vf2 v1 = poolPlane(A, t, h0ok);                         // plane 2k+1 finishes window k
        storeK(k, vmax2(acc, v1));
        A = loadPlane(base + (size_t)(2 * k + 3) * HW, r0off);  // issue next-plane loads
        vf2 v2 = poolPlane(B, t, h0ok);                         // plane 2k+2 starts window k+1
        acc = vmax2(v1, v2);
    }
    const int kl = k0 + KPB - 1;                                // last window of this chunk
    storeK(kl, vmax2(acc, poolPlane(A, t, h0ok)));
}

extern "C" void kernel_launch(void* const* d_in, const int* in_sizes, int n_in,
                              void* d_out, int out_size, void* d_ws, size_t ws_size,
                              hipStream_t stream) {
    const float* x = (const float*)d_in[0];
    float* out = (float*)d_out;
    dim3 grid(H_OUT / 16, D_OUT / KPB, NC);   // 4 x 4 x 64 = 1024 blocks
    dim3 block(512);
    maxpool3d_k3s2p1_v11<<<grid, block, 0, stream>>>(x, out);
}

// Round 12
// 118.265 us; speedup vs baseline: 1.1596x; 1.1596x over previous
//
#include <hip/hip_runtime.h>
#include <math.h>

// FINAL (best measured: 118.2 us, R5): MaxPool3d k=3 s=2 p=1 (-inf pad)
// in (2,32,128,128,128) f32 -> out (2,32,64,64,64) f32.
// Thread = 2x2 (h_out x w_out) patch sliding over d (d-eighth per block).
// 2-plane software pipeline (named register buffers A/B, no runtime indexing).
// Per plane: 5 float4 row-loads; left tap 4t-1 via shfl_up; nontemporal stores.
// Measured-null levers (kept simple): occupancy x2 (R8), chain /2 (R9), h-tile
// x2 (R10), XCD swizzle (R6); chain x2 regressed (R6/R11); forced VGPR cap
// spilled (R7). Implied BW ~5.3 TB/s on ~625 MB traffic = this access mix's
// achievable ceiling (copy ceiling 6.3 TB/s not reachable for strided 3D reads).

#define D_IN 128
#define H_IN 128
#define W_IN 128
#define HW (H_IN * W_IN)
#define D_OUT 64
#define H_OUT 64
#define W_OUT 64
#define NC 64   // 2*32
#define KPB 8   // d_out windows per block

typedef float vf2 __attribute__((ext_vector_type(2)));

struct P5 { float4 r0, r1, r2, r3, r4; };

__device__ __forceinline__ float4 fmax4(float4 a, float4 b) {
    return make_float4(fmaxf(a.x, b.x), fmaxf(a.y, b.y), fmaxf(a.z, b.z), fmaxf(a.w, b.w));
}

__device__ __forceinline__ P5 loadPlane(const float* __restrict__ p, int r0off) {
    P5 v;
    v.r0 = *reinterpret_cast<const float4*>(p + r0off);   // row h_in0 (clamped if pad)
    v.r1 = *reinterpret_cast<const float4*>(p + W_IN);
    v.r2 = *reinterpret_cast<const float4*>(p + 2 * W_IN);
    v.r3 = *reinterpret_cast<const float4*>(p + 3 * W_IN);
    v.r4 = *reinterpret_cast<const float4*>(p + 4 * W_IN);
    return v;
}

__device__ __forceinline__ float rowL(float4 v, int t) {
    float left = __shfl_up(v.w, 1, 64);   // neighbor's x[4t-1]
    if (t == 0) left = -INFINITY;         // -inf pad at w=-1 (also kills cross-half garbage)
    return fmaxf(left, fmaxf(v.x, v.y));  // w_out = 2t
}
__device__ __forceinline__ float rowR(float4 v) {
    return fmaxf(v.y, fmaxf(v.z, v.w));   // w_out = 2t+1
}

__device__ __forceinline__ float4 poolPlane(const P5& v, int t, bool h0ok) {
    float ax0 = rowL(v.r0, t), ay0 = rowR(v.r0);
    if (!h0ok) { ax0 = -INFINITY; ay0 = -INFINITY; }   // row -1 is -inf pad
    float ax1 = rowL(v.r1, t), ay1 = rowR(v.r1);
    float ax2 = rowL(v.r2, t), ay2 = rowR(v.r2);
    float ax3 = rowL(v.r3, t), ay3 = rowR(v.r3);
    float ax4 = rowL(v.r4, t), ay4 = rowR(v.r4);
    float4 o;
    o.x = fmaxf(ax0, fmaxf(ax1, ax2));
    o.y = fmaxf(ay0, fmaxf(ay1, ay2));
    o.z = fmaxf(ax2, fmaxf(ax3, ax4));
    o.w = fmaxf(ay2, fmaxf(ay3, ay4));
    return o;
}

__global__ __launch_bounds__(256) void maxpool3d_k3s2p1_final(const float* __restrict__ x,
                                                              float* __restrict__ out) {
    const int t  = threadIdx.x & 31;   // w-pair index: w_out = 2t, 2t+1
    const int hy = threadIdx.x >> 5;   // h-pair index within block (0..7)
    const int h_out0 = blockIdx.x * 16 + hy * 2;
    const int k0     = blockIdx.y * KPB;
    const int nc     = blockIdx.z;

    const int h_in0 = 2 * h_out0 - 1;
    const bool h0ok = (h_in0 >= 0);
    const int r0off = h0ok ? 0 : W_IN;   // clamp pad row's address (value replaced)

    const float* __restrict__ base =
        x + (size_t)nc * (D_IN * HW) + (ptrdiff_t)h_in0 * W_IN + 4 * t;
    float* __restrict__ obase =
        out + (size_t)nc * (D_OUT * H_OUT * W_OUT) + (size_t)h_out0 * W_OUT + 2 * t;

    auto storeK = [&](int k, float4 o) {
        float* orow = obase + (size_t)k * (H_OUT * W_OUT);
        vf2 lo = {o.x, o.y}, hi = {o.z, o.w};
        __builtin_nontemporal_store(lo, reinterpret_cast<vf2*>(orow));
        __builtin_nontemporal_store(hi, reinterpret_cast<vf2*>(orow + W_OUT));
    };

    P5 A, B;
    float4 acc;
    // Invariant: acc = max over planes {2k0-1, 2k0}; A holds plane 2k0+1 (issued).
    if (k0 == 0) {
        A = loadPlane(base, r0off);                           // plane 0 (plane -1 = pad)
        P5 A1 = loadPlane(base + HW, r0off);                  // plane 1, issued early
        acc = poolPlane(A, t, h0ok);
        A = A1;
    } else {
        A = loadPlane(base + (size_t)(2 * k0 - 1) * HW, r0off);
        B = loadPlane(base + (size_t)(2 * k0) * HW, r0off);
        float4 a0 = poolPlane(A, t, h0ok);
        A = loadPlane(base + (size_t)(2 * k0 + 1) * HW, r0off);
        acc = fmax4(a0, poolPlane(B, t, h0ok));
    }

#pragma unroll 1
    for (int k = k0; k < k0 + KPB - 1; ++k) {
        B = loadPlane(base + (size_t)(2 * k + 2) * HW, r0off);  // issue next-plane loads
        float4 v1 = poolPlane(A, t, h0ok);                      // plane 2k+1 finishes window k
        storeK(k, fmax4(acc, v1));
        A = loadPlane(base + (size_t)(2 * k + 3) * HW, r0off);  // issue next-plane loads
        float4 v2 = poolPlane(B, t, h0ok);                      // plane 2k+2 starts window k+1
        acc = fmax4(v1, v2);
    }
    const int kl = k0 + KPB - 1;                                // last window of this eighth
    storeK(kl, fmax4(acc, poolPlane(A, t, h0ok)));
}

extern "C" void kernel_launch(void* const* d_in, const int* in_sizes, int n_in,
                              void* d_out, int out_size, void* d_ws, size_t ws_size,
                              hipStream_t stream) {
    const float* x = (const float*)d_in[0];
    float* out = (float*)d_out;
    dim3 grid(H_OUT / 16, D_OUT / KPB, NC);   // 4 x 8 x 64 = 2048 blocks
    dim3 block(256);
    maxpool3d_k3s2p1_final<<<grid, block, 0, stream>>>(x, out);
}